// Round 3
// baseline (497.282 us; speedup 1.0000x reference)
//
#include <hip/hip_runtime.h>

#define N_NODES   200000
#define N_CHILD   32
#define N_LAYERS  8
#define NSLICE    8                       // table slices (one per block-column)
#define NGROUP    32                      // node groups (one per block-row)
#define SLICE     (N_NODES / NSLICE)      // 25000 floats = 100 KB LDS
#define GRP       (N_NODES / NGROUP)      // 6250 nodes per group
#define PBT       1024                    // partial kernel: 16 waves
#define NBATCH    ((GRP + PBT - 1) / PBT) // 7 node-batches per block
#define NWAVE     (PBT / 64)              // 16
#define SEG4      ((SLICE / 4 + 63) / 64) // 98 wave-segments of 64 float4
#define RBT       1024
#define RNB       ((N_NODES + RBT - 1) / RBT) // 196

#define AS1 __attribute__((address_space(1)))
#define AS3 __attribute__((address_space(3)))

// v6: table-slicing. v4/v5 post-mortem: staging rate (~6 B/cyc/CU) was
// insensitive to mechanism (vector loads vs DMA) and schedule (lockstep vs
// staggered) -> it's AGGREGATE beyond-L2 traffic: 256 CUs x 800 KB = 204.8
// MB/layer. Fix: each block stages only a 100 KB slice (25.6 MB/layer
// aggregate, 8x less) and emits partial sums; a tiny reduce kernel combines
// 8 partials + activation. child_idx is read 8x, but the 8 slice-blocks of
// a group are placed on the SAME XCD (b = xcd + 8*(g'*8+s)) reading the
// same 800 KB range concurrently -> L2/MSHR absorbs the replication.
__device__ __forceinline__ void stage_slice_async(const float4* __restrict__ src4,
                                                  float4* dst4, int wave, int lane)
{
    #pragma unroll
    for (int sg = 0; sg < (SEG4 + NWAVE - 1) / NWAVE; ++sg) {
        const int seg = wave + sg * NWAVE;
        const int e   = (seg << 6) + lane;          // float4 index within slice
        if (seg < SEG4 && e < SLICE / 4) {
            __builtin_amdgcn_global_load_lds(
                (const AS1 void*)(const void*)(src4 + e),
                (AS3 void*)(void*)(dst4 + e),
                16, 0, 0);
        }
    }
}

__global__ __launch_bounds__(PBT) void partial_kernel(
    const float* __restrict__ vals_in,
    float*       __restrict__ partials,     // [NSLICE][N_NODES]
    const int*   __restrict__ child_idx)    // [N_NODES][N_CHILD] this layer
{
    __shared__ __align__(16) float lds[SLICE];
    const int tid  = threadIdx.x;
    const int wave = tid >> 6;
    const int lane = tid & 63;

    // block -> (group, slice) with the 8 slices of a group on one XCD:
    // XCD = blockIdx % 8 (round-robin dispatch), so all b = xcd + 8k share an XCD.
    const int b   = blockIdx.x;
    const int xcd = b & 7;
    const int k   = b >> 3;                 // [0,32) within XCD
    const int g   = xcd * 4 + (k >> 3);     // 4 groups per XCD
    const int s   = k & 7;                  // slice
    const unsigned sbase = (unsigned)(s * SLICE);
    const int nbase = g * GRP;

    // stage this block's slice (async DMA); overlaps batch-0 child_idx loads
    stage_slice_async((const float4*)vals_in + (size_t)s * (SLICE / 4),
                      (float4*)lds, wave, lane);

    #pragma unroll 1
    for (int bt = 0; bt < NBATCH; ++bt) {
        const int n      = bt * PBT + tid;      // node offset within group
        const bool act   = (n < GRP);
        const int node   = nbase + n;

        int idx[N_CHILD];
        if (act) {
            const int4* ci = (const int4*)(child_idx + (size_t)node * N_CHILD);
            #pragma unroll
            for (int j = 0; j < N_CHILD / 4; ++j) {
                int4 c = ci[j];
                idx[4*j+0] = c.x; idx[4*j+1] = c.y;
                idx[4*j+2] = c.z; idx[4*j+3] = c.w;
            }
        } else {
            #pragma unroll
            for (int j = 0; j < N_CHILD; ++j) idx[j] = 0;
        }

        if (bt == 0) __syncthreads();   // slice fully staged (vmcnt0 drain)

        float acc = 0.0f;
        #pragma unroll
        for (int j = 0; j < N_CHILD; ++j) {
            unsigned off = (unsigned)idx[j] - sbase;
            bool in  = off < (unsigned)SLICE;
            float v  = lds[in ? off : 0u];   // always in-bounds, no branch
            acc += in ? v : 0.0f;            // cndmask, no branch
        }
        if (act) partials[(size_t)s * N_NODES + node] = acc;
    }
}

__global__ __launch_bounds__(RBT) void reduce_kernel(
    const float* __restrict__ partials,     // [NSLICE][N_NODES]
    float*       __restrict__ vals_out,
    const int*   __restrict__ fun_ids,      // [N_NODES] this layer
    const float* __restrict__ wptr)
{
    const int node = blockIdx.x * RBT + threadIdx.x;
    if (node >= N_NODES) return;
    float ssum = 0.0f;
    #pragma unroll
    for (int s = 0; s < NSLICE; ++s)
        ssum += partials[(size_t)s * N_NODES + node];
    const float x = wptr[0] * ssum;
    const int fid = fun_ids[node];
    float y;
    if (fid == 0)      y = tanhf(x);
    else if (fid == 1) y = 1.0f / (1.0f + __expf(-x));  // safe at +-inf
    else if (fid == 2) y = fmaxf(x, 0.0f);
    else               y = x;
    vals_out[node] = y;
}

extern "C" void kernel_launch(void* const* d_in, const int* in_sizes, int n_in,
                              void* d_out, int out_size, void* d_ws, size_t ws_size,
                              hipStream_t stream) {
    const float* X         = (const float*)d_in[0];
    const float* w         = (const float*)d_in[1];
    const int*   child_idx = (const int*)d_in[2];
    const int*   fun_ids   = (const int*)d_in[3];
    float*       out       = (float*)d_out;
    float*       bufA      = (float*)d_ws;                        // 800 KB vals ping
    float*       partials  = (float*)((char*)d_ws + 800000);      // 6.4 MB, 16B-aligned

    const float* cur = X;
    for (int l = 0; l < N_LAYERS; ++l) {
        // even layers -> bufA, odd layers -> d_out; layer 7 (last) -> d_out
        float* nxt = (l & 1) ? out : bufA;
        partial_kernel<<<NGROUP * NSLICE, PBT, 0, stream>>>(
            cur, partials,
            child_idx + (size_t)l * N_NODES * N_CHILD);
        reduce_kernel<<<RNB, RBT, 0, stream>>>(
            partials, nxt,
            fun_ids + (size_t)l * N_NODES,
            w);
        cur = nxt;
    }
}

// Round 5
// 388.805 us; speedup vs baseline: 1.2790x; 1.2790x over previous
//
#include <hip/hip_runtime.h>

#define N_NODES  200000
#define N_CHILD  32
#define N_LAYERS 8
#define CHUNK    40000   // bf16 per window; 2 windows * 80000 B = 160000 B LDS (max 163840)
#define NCHUNK   5       // 5 * 40000 = 200000 exactly
#define NB       256     // 1 block per CU
#define NPB      782     // ceil(200000/256) nodes per block
#define BT       832     // 13 waves; 782/832 = 94% lanes active
#define NWAVE    (BT / 64)            // 13
#define W16      (CHUNK / 8)          // 16B units per window = 5000
#define NSEG     ((W16 + 63) / 64)    // 79 wave-segments (seg 78 partial: 8 lanes)

#define AS1 __attribute__((address_space(1)))
#define AS3 __attribute__((address_space(3)))

// v8: bf16 value table. R0-R3 invariant: wall time tracks BYTES MOVED PER CU
// (~900 KB/layer at ~6.7 B/cyc) regardless of mechanism (loads vs DMA),
// schedule (stagger), or structure (slicing just swapped vals bytes for
// child_idx bytes). R4's counted-vmcnt pipeline raced -> reverted to the
// VERIFIED R1 structure (async global_load_lds, double-buffer, __syncthreads)
// and attack the bytes instead: store inter-layer values as bf16 (exact
// expansion on probe, RNE on store). Staged vals: 800->400 KB/CU. Windows
// grow to 40000 values (80 KB), so only 5 windows -> fewer barrier drains.
__device__ __forceinline__ void stage_window_async(const ushort* __restrict__ src,
                                                   ushort* dst, int wave, int lane)
{
    #pragma unroll
    for (int sg = 0; sg < (NSEG + NWAVE - 1) / NWAVE; ++sg) {
        const int seg = wave + sg * NWAVE;
        const int e   = (seg << 6) + lane;          // 16B-unit index within window
        if (seg < NSEG && e < W16) {
            __builtin_amdgcn_global_load_lds(
                (const AS1 void*)(const void*)(src + (size_t)e * 8),
                (AS3 void*)(void*)(dst + (size_t)e * 8),
                16, 0, 0);
        }
    }
}

__device__ __forceinline__ ushort f32_to_bf16_rne(float x) {
    unsigned u = __builtin_bit_cast(unsigned, x);
    u += 0x7FFFu + ((u >> 16) & 1u);
    return (ushort)(u >> 16);
}

__global__ __launch_bounds__(1024) void cvt_kernel(const float4* __restrict__ x4,
                                                   ushort4* __restrict__ o4) {
    const int i = blockIdx.x * 1024 + threadIdx.x;   // 50000 float4 total
    if (i < N_NODES / 4) {
        float4 v = x4[i];
        ushort4 r;
        r.x = f32_to_bf16_rne(v.x); r.y = f32_to_bf16_rne(v.y);
        r.z = f32_to_bf16_rne(v.z); r.w = f32_to_bf16_rne(v.w);
        o4[i] = r;
    }
}

template<bool LAST>
__global__ __launch_bounds__(BT) void layer_kernel(
    const ushort* __restrict__ vals_in,    // bf16 table [N_NODES]
    void*         __restrict__ vals_out,   // bf16 (mid) or f32 (last layer)
    const int*    __restrict__ child_idx,  // [N_NODES][N_CHILD] this layer
    const int*    __restrict__ fun_ids,    // [N_NODES] this layer
    const float*  __restrict__ wptr)
{
    __shared__ __align__(16) ushort lds[2][CHUNK];
    const int tid    = threadIdx.x;
    const int wave   = tid >> 6;
    const int lane   = tid & 63;
    const int node   = blockIdx.x * NPB + tid;
    const bool active = (tid < NPB) && (node < N_NODES);

    // get window 0 in flight before anything else
    stage_window_async(vals_in, lds[0], wave, lane);

    // child indices -> registers (8x int4, coalesced); overlaps with stage(0)
    int idx[N_CHILD];
    int fid = 3;
    if (active) {
        const int4* ci = (const int4*)(child_idx + (size_t)node * N_CHILD);
        #pragma unroll
        for (int j = 0; j < N_CHILD / 4; ++j) {
            int4 c = ci[j];
            idx[4*j+0] = c.x; idx[4*j+1] = c.y;
            idx[4*j+2] = c.z; idx[4*j+3] = c.w;
        }
        fid = fun_ids[node];
    } else {
        #pragma unroll
        for (int j = 0; j < N_CHILD; ++j) idx[j] = 0;
    }

    __syncthreads();   // vmcnt(0) drain: window 0 fully staged by all waves

    float s = 0.0f;
    #pragma unroll 1
    for (int c = 0; c < NCHUNK; ++c) {
        // issue next window's DMA first -- its latency hides under the probes
        if (c + 1 < NCHUNK)
            stage_window_async(vals_in + (size_t)(c + 1) * CHUNK,
                               lds[(c + 1) & 1], wave, lane);

        const ushort* __restrict__ buf = lds[c & 1];
        const unsigned cbase = (unsigned)(c * CHUNK);
        #pragma unroll
        for (int j = 0; j < N_CHILD; ++j) {
            unsigned off = (unsigned)idx[j] - cbase;
            bool in   = off < (unsigned)CHUNK;
            ushort rw = buf[in ? off : 0u];                       // in-bounds, no branch
            float v   = __builtin_bit_cast(float, (unsigned)rw << 16);  // exact bf16->f32
            s += in ? v : 0.0f;                                   // cndmask, no branch
        }
        // probes done (lgkmcnt) + stage(c+1) complete (vmcnt) + barrier
        __syncthreads();
    }

    if (active) {
        float x = wptr[0] * s;
        float y;
        if (fid == 0)      y = tanhf(x);
        else if (fid == 1) y = 1.0f / (1.0f + __expf(-x));  // safe at +-inf
        else if (fid == 2) y = fmaxf(x, 0.0f);
        else               y = x;
        if (LAST) ((float*)vals_out)[node]  = y;
        else      ((ushort*)vals_out)[node] = f32_to_bf16_rne(y);
    }
}

extern "C" void kernel_launch(void* const* d_in, const int* in_sizes, int n_in,
                              void* d_out, int out_size, void* d_ws, size_t ws_size,
                              hipStream_t stream) {
    const float* X         = (const float*)d_in[0];
    const float* w         = (const float*)d_in[1];
    const int*   child_idx = (const int*)d_in[2];
    const int*   fun_ids   = (const int*)d_in[3];
    float*       out       = (float*)d_out;
    ushort*      bufA      = (ushort*)d_ws;                      // 400 KB bf16 ping
    ushort*      bufB      = (ushort*)((char*)d_ws + 512000);    // 400 KB bf16 pong

    // X -> bf16 into bufA
    cvt_kernel<<<(N_NODES / 4 + 1023) / 1024, 1024, 0, stream>>>(
        (const float4*)X, (ushort4*)bufA);

    const ushort* cur = bufA;
    for (int l = 0; l < N_LAYERS; ++l) {
        const int*   ci = child_idx + (size_t)l * N_NODES * N_CHILD;
        const int*   fi = fun_ids   + (size_t)l * N_NODES;
        if (l == N_LAYERS - 1) {
            layer_kernel<true><<<NB, BT, 0, stream>>>(cur, (void*)out, ci, fi, w);
        } else {
            ushort* nxt = (l & 1) ? bufA : bufB;   // l0:A->B, l1:B->A, ...
            layer_kernel<false><<<NB, BT, 0, stream>>>(cur, (void*)nxt, ci, fi, w);
            cur = nxt;
        }
    }
}